// Round 10
// baseline (264.066 us; speedup 1.0000x reference)
//
#include <hip/hip_runtime.h>
#include <hip/hip_bf16.h>
#include <stdint.h>

// ---------------------------------------------------------------------------
// SARoutingBlock. Round 17: gemm staging via global_load_lds width=16,
// isolating the staging half of R12's conflated A/B (tile-size change was the
// regression; the gload_lds+swizzle pattern passed correctness there and the
// 64^2 kernel's LDS layout is identical). 64^2 tile / BK=64 / 16KB LDS /
// 2370-block grid kept bit-for-bit; only the {uint4 load + ds_write + reg
// prefetch} staging is replaced by 4x global_load_lds per K-step (2-barrier
// m97 loop; 10 blocks/CU hide the drain). Riders + all other kernels
// bit-identical to Round 16 (best: 262.7 us).
// ---------------------------------------------------------------------------

typedef __bf16 bf16x8 __attribute__((ext_vector_type(8)));
typedef float f32x4 __attribute__((ext_vector_type(4)));

#define NEGV -1e9f
// sign-extended single-bit extract: bit 'off' of x -> 0x0 / 0xFFFFFFFF
#define SBFE(x, off) (((int)((x) << (31 - (off)))) >> 31)

__device__ __forceinline__ float b2f(unsigned short h) {
    union { unsigned int u; float f; } x; x.u = ((unsigned int)h) << 16; return x.f;
}
__device__ __forceinline__ unsigned short f2b(float f) {
    union { float f; unsigned int u; } x; x.f = f;
    unsigned int u = x.u + 0x7FFFu + ((x.u >> 16) & 1u);
    return (unsigned short)(u >> 16);
}
__device__ __forceinline__ unsigned int packbf(unsigned int u0, unsigned int u1) {
    unsigned int r0 = (u0 + 0x7FFFu + ((u0 >> 16) & 1u)) >> 16;
    unsigned int r1 = (u1 + 0x7FFFu + ((u1 >> 16) & 1u)) & 0xFFFF0000u;
    return r0 | r1;
}
__device__ __forceinline__ uint4 load8bf(const void* base, size_t elemOff, int isF32) {
    if (!isF32) return *(const uint4*)((const unsigned short*)base + elemOff);
    const uint4* f = (const uint4*)((const float*)base + elemOff);
    uint4 a = f[0], b = f[1];
    uint4 r;
    r.x = packbf(a.x, a.y);
    r.y = packbf(a.z, a.w);
    r.z = packbf(b.x, b.y);
    r.w = packbf(b.z, b.w);
    return r;
}
__device__ __forceinline__ float loadF(const void* p, int idx, int isF32) {
    return isF32 ? ((const float*)p)[idx] : b2f(((const unsigned short*)p)[idx]);
}
// async global->LDS, 16B per lane: lane l lands at ldsBase + l*16 (linear).
__device__ __forceinline__ void gload16(const unsigned short* g, unsigned short* l) {
    __builtin_amdgcn_global_load_lds(
        (__attribute__((address_space(1))) void*)g,
        (__attribute__((address_space(3))) void*)l,
        16, 0, 0);
}

// ---------------------------------------------------------------------------
// Sniffer: flags[0]=mask mode (0=i32,1=u8,2=f32,3=bf16); flags[1]=v/k/q dtype
// (0=bf16,1=f32); flags[2]=weights dtype. Also zeroes the hid/alpha
// accumulators (lg, cnt) for this iteration.
// ---------------------------------------------------------------------------
__global__ void sniff_kernel(const unsigned int* __restrict__ mp,
                             const unsigned int* __restrict__ vp,
                             const unsigned int* __restrict__ wp,
                             int* __restrict__ flags,
                             float* __restrict__ lg, int* __restrict__ cnt)
{
    __shared__ int oki, oku, okf, badv, badw;
    if (threadIdx.x < 24) lg[threadIdx.x] = 0.f;
    if (threadIdx.x >= 32 && threadIdx.x < 40) cnt[threadIdx.x - 32] = 0;
    if (threadIdx.x == 0) { oki = 1; oku = 1; okf = 1; badv = 0; badw = 0; }
    __syncthreads();
    int li = 1, lu = 1, lf = 1, bv = 0, bw = 0;
    const uint4* m4 = (const uint4*)mp;
    for (int i = threadIdx.x; i < 4096; i += 256) {
        uint4 u = m4[i];
        unsigned int ws[4] = {u.x, u.y, u.z, u.w};
        #pragma unroll
        for (int j = 0; j < 4; j++) {
            unsigned int w = ws[j];
            if (w > 1u) li = 0;
            if (w & 0xFEFEFEFEu) lu = 0;
            if (w != 0u && w != 0x3F800000u) lf = 0;
        }
    }
    const uint4* v4 = (const uint4*)vp;
    const uint4* w4 = (const uint4*)wp;
    for (int i = threadIdx.x; i < 2048; i += 256) {
        uint4 u = v4[i];
        uint4 u2 = w4[i];
        unsigned int wa[4] = {u.x, u.y, u.z, u.w};
        unsigned int wb[4] = {u2.x, u2.y, u2.z, u2.w};
        #pragma unroll
        for (int j = 0; j < 4; j++) {
            float f0 = b2f((unsigned short)(wa[j] & 0xFFFF));
            float f1 = b2f((unsigned short)(wa[j] >> 16));
            if (!(fabsf(f0) < 1e4f) || !(fabsf(f1) < 1e4f)) bv = 1;
            f0 = b2f((unsigned short)(wb[j] & 0xFFFF));
            f1 = b2f((unsigned short)(wb[j] >> 16));
            if (!(fabsf(f0) < 1e4f) || !(fabsf(f1) < 1e4f)) bw = 1;
        }
    }
    if (!li) atomicAnd(&oki, 0);
    if (!lu) atomicAnd(&oku, 0);
    if (!lf) atomicAnd(&okf, 0);
    if (bv) atomicOr(&badv, 1);
    if (bw) atomicOr(&badw, 1);
    __syncthreads();
    if (threadIdx.x == 0) {
        flags[0] = oki ? 0 : (oku ? 1 : (okf ? 2 : 3));
        flags[1] = badv;
        flags[2] = badw;
    }
}

// ---------------------------------------------------------------------------
// prep_kernel: fused conv_act (blocks 0..4607; early-exit when activations
// are already bf16) + conv_wt (4608..5183) + pack (5184..5567) +
// route_score (5568..5631). One launch; LDS union.
// ---------------------------------------------------------------------------
__global__ __launch_bounds__(256) void prep_kernel(
        const void* __restrict__ v, const void* __restrict__ k,
        const void* __restrict__ q,
        const void* __restrict__ W0, const void* __restrict__ W1,
        const void* __restrict__ W2, const void* __restrict__ W3,
        const void* __restrict__ masks,
        const void* __restrict__ pool_w, const void* __restrict__ pool_b,
        const int* __restrict__ flags,
        unsigned short* __restrict__ vb, unsigned short* __restrict__ kb,
        unsigned short* __restrict__ qb,
        unsigned short* __restrict__ T0, unsigned short* __restrict__ T1,
        unsigned short* __restrict__ T2, unsigned short* __restrict__ T3,
        unsigned int* __restrict__ pm, float* __restrict__ scores)
{
    __shared__ unsigned char shm[16384];
    const int t = threadIdx.x;
    const int id = blockIdx.x;

    if (id < 4608) {
        // ---- conv_act: only needed when activations are f32 ----
        const int dtV = flags[1];
        if (!dtV) return;             // bf16 input: gemm reads raw directly
        const int which = id / 1536, bx = id % 1536;
        const void* src = (which == 0) ? v : (which == 1) ? k : q;
        unsigned short* dst = (which == 0) ? vb : (which == 1) ? kb : qb;
        size_t off = ((size_t)bx * 256 + t) * 8;
        uint4 r = load8bf(src, off, 1);
        *(uint4*)(dst + off) = r;
        return;
    }

    if (id < 5184) {
        // ---- conv_wt: W[768][768] -> WT bf16 [n][k] (transposed) ----
        const int id2 = id - 4608;
        const int which = id2 / 144, bxw = id2 % 144;
        const int dtW = flags[2];
        const void* W = (which == 0) ? W0 : (which == 1) ? W1 : (which == 2) ? W2 : W3;
        unsigned short* T = (which == 0) ? T0 : (which == 1) ? T1 : (which == 2) ? T2 : T3;
        unsigned short (*tile)[65] = (unsigned short (*)[65])shm;   // 8320 B
        const int tk = (bxw / 12) << 6;
        const int tn = (bxw % 12) << 6;
        #pragma unroll
        for (int i = 0; i < 16; i++) {
            int idx = (i << 8) + t;
            int r = idx >> 6, c = idx & 63;
            tile[r][c] = f2b(loadF(W, (tk + r) * 768 + tn + c, dtW));
        }
        __syncthreads();
        #pragma unroll
        for (int i = 0; i < 16; i++) {
            int idx = (i << 8) + t;
            int rn = idx >> 6, ck = idx & 63;
            T[(size_t)(tn + rn) * 768 + tk + ck] = tile[ck][rn];
        }
        return;
    }

    if (id < 5568) {
        // ---- pack: mask bit-pack (R9 layout). One block packs 32 rows ----
        const int pb = id - 5184;
        unsigned char* flg = shm;                                    // 16384 B
        const int mode = flags[0];
        const size_t e0 = (size_t)pb * (32 * 512);
        if (mode == 0 || mode == 2) {
            const uint4* p = (const uint4*)((const unsigned int*)masks + e0);
            for (int i = t; i < 4096; i += 256) {
                uint4 u = p[i];
                int base = i << 2;
                flg[base + 0] = u.x ? 1 : 0;
                flg[base + 1] = u.y ? 1 : 0;
                flg[base + 2] = u.z ? 1 : 0;
                flg[base + 3] = u.w ? 1 : 0;
            }
        } else if (mode == 1) {
            const uint4* p = (const uint4*)((const unsigned char*)masks + e0);
            for (int i = t; i < 1024; i += 256) {
                uint4 u = p[i];
                unsigned int uu[4] = {u.x, u.y, u.z, u.w};
                int base = i << 4;
                #pragma unroll
                for (int k2 = 0; k2 < 4; k2++)
                    #pragma unroll
                    for (int bb = 0; bb < 4; bb++)
                        flg[base + k2 * 4 + bb] = ((uu[k2] >> (bb * 8)) & 0xFFu) ? 1 : 0;
            }
        } else {
            const uint4* p = (const uint4*)((const unsigned short*)masks + e0);
            for (int i = t; i < 2048; i += 256) {
                uint4 u = p[i];
                unsigned int uu[4] = {u.x, u.y, u.z, u.w};
                int base = i << 3;
                #pragma unroll
                for (int k2 = 0; k2 < 4; k2++) {
                    flg[base + k2 * 2 + 0] = (uu[k2] & 0xFFFFu) ? 1 : 0;
                    flg[base + k2 * 2 + 1] = (uu[k2] >> 16) ? 1 : 0;
                }
            }
        }
        __syncthreads();
        const int lbi = pb >> 4;            // l*8 + b
        const int qb0 = (pb & 15) << 1;     // first of 2 qb16 chunks
        for (int widx = t; widx < 512; widx += 256) {
            const int qq = widx >> 8, sub = widx & 255;
            const int w2 = sub >> 6, lm = (sub >> 2) & 15, quad = sub & 3;
            const unsigned char* fr = &flg[(((qq << 4) + (quad << 2)) << 9) + lm];
            unsigned int bits = 0;
            #pragma unroll
            for (int rg = 0; rg < 4; rg++)
                #pragma unroll
                for (int nt = 0; nt < 8; nt++)
                    bits |= ((unsigned int)(fr[(rg << 9) + (((w2 << 3) + nt) << 4)] & 1u))
                            << ((rg << 3) + nt);
            pm[(size_t)lbi * 8192 + (size_t)(qb0 + qq) * 256 + sub] = bits;
        }
        return;
    }

    // ---- route_score: raw pooling scores (64 rows/block, 4 thr/row) ----
    const int sid = id - 5568;
    const int b = sid >> 3, ch = sid & 7;
    const int dtV = flags[1], dtW = flags[2];
    float* pw = (float*)shm;                                        // 3072 B
    for (int d = t; d < 768; d += 256) pw[d] = loadF(pool_w, d, dtW);
    __syncthreads();
    const int r = t >> 2, c4 = t & 3;
    const int n = (ch << 6) + r;
    float dot = 0.f, asum = 0.f;
    if (!dtV) {
        const unsigned int* vr = (const unsigned int*)v + ((size_t)(b * 512 + n)) * 384;
        for (int j = 0; j < 96; j++) {
            int p = c4 + (j << 2);
            unsigned int u = vr[p];
            float f0 = b2f((unsigned short)(u & 0xFFFF));
            float f1 = b2f((unsigned short)(u >> 16));
            asum += fabsf(f0) + fabsf(f1);
            dot += f0 * pw[2 * p] + f1 * pw[2 * p + 1];
        }
    } else {
        const float* vf = (const float*)v + ((size_t)(b * 512 + n)) * 768;
        for (int j = 0; j < 48; j++) {
            float4 u = ((const float4*)vf)[c4 + (j << 2)];
            int e = (c4 + (j << 2)) << 2;
            asum += fabsf(u.x) + fabsf(u.y) + fabsf(u.z) + fabsf(u.w);
            dot += u.x * pw[e] + u.y * pw[e + 1] + u.z * pw[e + 2] + u.w * pw[e + 3];
        }
    }
    dot += __shfl_xor(dot, 1); dot += __shfl_xor(dot, 2);
    asum += __shfl_xor(asum, 1); asum += __shfl_xor(asum, 2);
    if (c4 == 0)
        scores[b * 512 + n] = (asum == 0.f) ? NEGV : dot + loadF(pool_b, 0, dtW);
}

// ---------------------------------------------------------------------------
// route_hid (+fused alpha): hidden units + partial logits; the last block of
// each batch (atomic counter) finalizes softmax -> alphas. Grid (12,8).
// ---------------------------------------------------------------------------
__global__ __launch_bounds__(256) void route_hid_kernel(
        const void* __restrict__ w1, const void* __restrict__ w2,
        const void* __restrict__ b2, const int* __restrict__ flags,
        const float* __restrict__ ppart,
        float* __restrict__ lg, int* __restrict__ cnt,
        float* __restrict__ alphas)
{
    __shared__ float pool[768];
    __shared__ float red[4][32];
    const int t = threadIdx.x;
    const int jc = blockIdx.x, b = blockIdx.y;
    const int dtW = flags[2];
    for (int d = t; d < 768; d += 256) {
        float a = 0.f;
        #pragma unroll
        for (int c = 0; c < 8; c++) a += ppart[((size_t)(b * 8 + c)) * 768 + d];
        pool[d] = a;
    }
    __syncthreads();
    const int jo = (t & 3) << 3;
    const int dr = t >> 2;
    float acc[8];
    #pragma unroll
    for (int j = 0; j < 8; j++) acc[j] = 0.f;
    for (int it = 0; it < 12; it++) {
        int d = (it << 6) + dr;
        float pv = pool[d];
        size_t off = (size_t)d * 384 + (jc << 5) + jo;
        if (!dtW) {
            uint4 u = *(const uint4*)((const unsigned short*)w1 + off);
            unsigned int uu[4] = {u.x, u.y, u.z, u.w};
            #pragma unroll
            for (int j2 = 0; j2 < 4; j2++) {
                acc[2 * j2]     += pv * b2f((unsigned short)(uu[j2] & 0xFFFF));
                acc[2 * j2 + 1] += pv * b2f((unsigned short)(uu[j2] >> 16));
            }
        } else {
            const float4* f = (const float4*)((const float*)w1 + off);
            float4 u0 = f[0], u1 = f[1];
            acc[0] += pv * u0.x; acc[1] += pv * u0.y;
            acc[2] += pv * u0.z; acc[3] += pv * u0.w;
            acc[4] += pv * u1.x; acc[5] += pv * u1.y;
            acc[6] += pv * u1.z; acc[7] += pv * u1.w;
        }
    }
    #pragma unroll
    for (int off = 4; off < 64; off <<= 1)
        #pragma unroll
        for (int j = 0; j < 8; j++) acc[j] += __shfl_xor(acc[j], off);
    const int w = t >> 6, lane = t & 63;
    if (lane < 4) {
        #pragma unroll
        for (int j = 0; j < 8; j++) red[w][lane * 8 + j] = acc[j];
    }
    __syncthreads();
    if (t < 32) {
        float h = red[0][t] + red[1][t] + red[2][t] + red[3][t];
        h = fmaxf(h, 0.f);
        int jg = (jc << 5) + t;
        float l0 = h * loadF(w2, jg * 3 + 0, dtW);
        float l1 = h * loadF(w2, jg * 3 + 1, dtW);
        float l2 = h * loadF(w2, jg * 3 + 2, dtW);
        #pragma unroll
        for (int off = 1; off < 32; off <<= 1) {
            l0 += __shfl_xor(l0, off);
            l1 += __shfl_xor(l1, off);
            l2 += __shfl_xor(l2, off);
        }
        if (t == 0) {
            atomicAdd(&lg[b * 3 + 0], l0);
            atomicAdd(&lg[b * 3 + 1], l1);
            atomicAdd(&lg[b * 3 + 2], l2);
            __threadfence();
            int old = atomicAdd(&cnt[b], 1);
            if (old == 11) {             // last block for this batch: finalize
                __threadfence();
                float g0 = atomicAdd(&lg[b * 3 + 0], 0.f) + loadF(b2, 0, dtW);
                float g1 = atomicAdd(&lg[b * 3 + 1], 0.f) + loadF(b2, 1, dtW);
                float g2 = atomicAdd(&lg[b * 3 + 2], 0.f) + loadF(b2, 2, dtW);
                float mm = fmaxf(g0, fmaxf(g1, g2));
                float e0 = __expf(g0 - mm), e1 = __expf(g1 - mm), e2 = __expf(g2 - mm);
                float ss = e0 + e1 + e2;
                alphas[b * 3 + 0] = e0 / ss;
                alphas[b * 3 + 1] = e1 / ss;
                alphas[b * 3 + 2] = e2 / ss;
            }
        }
    }
}

// ---------------------------------------------------------------------------
// Pipelined MFMA bf16 GEMM (64^2 tile) + route_sp rider blocks.
// Staging now via global_load_lds width=16 (rule-21: linear LDS dest,
// inverse-swizzled per-lane global source, XOR-swizzled ds_read_b128 frags —
// LDS layout identical to the previous ds_write version). 2-barrier K-loop.
// Up to 3 sub-gemms by blockIdx.y (x < 768); x >= 768 are route_sp riders.
// mode 0: dst[b][h][n][64]; mode 1: dst[row][col] (bf16/f32); mode 2: V^T.
// ---------------------------------------------------------------------------
__global__ __launch_bounds__(256) void gemm3_kernel(
        const unsigned short* __restrict__ X0, const unsigned short* __restrict__ X1,
        const unsigned short* __restrict__ X2,
        const void* __restrict__ R0, const void* __restrict__ R1,
        const void* __restrict__ R2,
        const unsigned short* __restrict__ W0, const unsigned short* __restrict__ W1,
        const unsigned short* __restrict__ W2,
        const void* __restrict__ bias0, const void* __restrict__ bias1,
        const void* __restrict__ bias2,
        const int* __restrict__ flags,
        void* __restrict__ dst0, void* __restrict__ dst1, void* __restrict__ dst2,
        int m0, int m1, int m2,
        const float* __restrict__ scores, float* __restrict__ ppart)
{
    __shared__ unsigned short smem[8192];   // At[4096] + Bt[4096], 16 KB
    const int t = threadIdx.x;
    const int dtW = flags[2];
    const int dtOut = flags[1];

    if (blockIdx.x >= 768) {
        // ---- route_sp rider: fused softmax + pool (64 active blocks) ----
        const int rid = (blockIdx.x - 768) * 3 + blockIdx.y;
        if (rid >= 64) return;
        float* red = (float*)smem;          // 4 floats
        float* sl  = red + 4;               // 64 floats
        const int b = rid >> 3, ch = rid & 7;
        const int dtV = dtOut;

        float s0 = scores[b * 512 + t];
        float s1 = scores[b * 512 + 256 + t];
        float mx = fmaxf(s0, s1);
        #pragma unroll
        for (int off = 1; off < 64; off <<= 1) mx = fmaxf(mx, __shfl_xor(mx, off));
        if ((t & 63) == 0) red[t >> 6] = mx;
        __syncthreads();
        const float M = fmaxf(fmaxf(red[0], red[1]), fmaxf(red[2], red[3]));
        float e = __expf(s0 - M) + __expf(s1 - M);
        __syncthreads();
        float sm = e;
        #pragma unroll
        for (int off = 1; off < 64; off <<= 1) sm += __shfl_xor(sm, off);
        if ((t & 63) == 0) red[t >> 6] = sm;
        __syncthreads();
        const float SS = red[0] + red[1] + red[2] + red[3];

        if (t < 64) {
            float sc = scores[b * 512 + (ch << 6) + t];
            sl[t] = __expf(sc - M) / SS;
        }
        __syncthreads();

        const int d0 = t * 3;
        float a0 = 0.f, a1 = 0.f, a2 = 0.f;
        if (!dtV) {
            const unsigned short* vp = (const unsigned short*)R0
                + ((size_t)(b * 512 + (ch << 6))) * 768 + d0;
            #pragma unroll 4
            for (int r = 0; r < 64; r++) {
                float p = sl[r];
                a0 += b2f(vp[0]) * p; a1 += b2f(vp[1]) * p; a2 += b2f(vp[2]) * p;
                vp += 768;
            }
        } else {
            const float* vp = (const float*)R0 + ((size_t)(b * 512 + (ch << 6))) * 768 + d0;
            #pragma unroll 4
            for (int r = 0; r < 64; r++) {
                float p = sl[r];
                a0 += vp[0] * p; a1 += vp[1] * p; a2 += vp[2] * p;
                vp += 768;
            }
        }
        float* o = ppart + ((size_t)(b * 8 + ch)) * 768 + d0;
        o[0] = a0; o[1] = a1; o[2] = a2;
        return;
    }

    unsigned short* At = smem;
    unsigned short* Bt = smem + 4096;
    const int which = blockIdx.y;
    const unsigned short* Xc = (which == 0) ? X0 : (which == 1) ? X1 : X2;
    const void* Xr = (which == 0) ? R0 : (which == 1) ? R1 : R2;
    const unsigned short* X = dtOut ? Xc : (const unsigned short*)Xr;
    const unsigned short* WT = (which == 0) ? W0 : (which == 1) ? W1 : W2;
    const void* bias = (which == 0) ? bias0 : (which == 1) ? bias1 : bias2;
    void* dst = (which == 0) ? dst0 : (which == 1) ? dst1 : dst2;
    const int mode = (which == 0) ? m0 : (which == 1) ? m1 : m2;

    const int id = blockIdx.x;
    const int bx = id >> 6, by = id & 63;
    const int row0 = by << 6, col0 = bx << 6;
    const int w = t >> 6, lane = t & 63, quad = lane >> 4, lm = lane & 15;

    // staging (global_load_lds): wave w covers rows w*16..+15 of both tiles
    // in 2 issues of 8 rows each. Lane l: row (l>>3) within the 8-row group,
    // source k-granule (l&7)^(l>>3) [inverse swizzle]; LDS dest linear
    // (HW adds lane*16 to the wave-uniform base).
    const int lr8 = lane >> 3;                       // 0..7
    const int lc8 = (((lane & 7) ^ lr8) << 3);       // pre-swizzled granule
    const unsigned short* gax = X  + (size_t)(row0 + (w << 4) + lr8) * 768 + lc8;
    const unsigned short* gbx = WT + (size_t)(col0 + (w << 4) + lr8) * 768 + lc8;
    unsigned short* lax = At + (w << 10);            // w*16 rows * 64 shorts
    unsigned short* lbx = Bt + (w << 10);

    f32x4 acc[4];
    #pragma unroll
    for (int i = 0; i < 4; i++) acc[i] = (f32x4){0.f, 0.f, 0.f, 0.f};

    const int am = (w << 4) + lm;
    const int abase = am * 64, akey = (am & 7) << 3;

    for (int k0 = 0; k0 < 768; k0 += 64) {
        __syncthreads();                 // prior step's frag reads complete
        #pragma unroll
        for (int i = 0; i < 2; i++) {
            gload16(gax + (i << 3) * 768 + k0, lax + (i << 9));
            gload16(gbx + (i << 3) * 768 + k0, lbx + (i << 9));
        }
        __syncthreads();                 // drains vmcnt -> tiles ready
        #pragma unroll
        for (int ks = 0; ks < 2; ks++) {
            int ko = (quad << 3) + (ks << 5);
            bf16x8 afr = *(const bf16x8*)&At[abase + (ko ^ akey)];
            #pragma unroll
            for (int t4 = 0; t4 < 4; t4++) {
                int bn = (t4 << 4) + lm;
                bf16x8 bfr = *(const bf16x8*)&Bt[bn * 64 + (ko ^ ((bn & 7) << 3))];
                acc[t4] = __builtin_amdgcn_mfma_f32_16x16x32_bf16(afr, bfr, acc[t4], 0, 0, 0);
            }
        }
    }

    if (mode == 1 && dtOut) {
        #pragma unroll
        for (int t4 = 0; t4 < 4; t4++) {
            int col = col0 + (t4 << 4) + lm;
            float bsv = loadF(bias, col, dtW);
            #pragma unroll
            for (int rg = 0; rg < 4; rg++) {
                int row = row0 + (w << 4) + (quad << 2) + rg;
                ((float*)dst)[(size_t)row * 768 + col] = acc[t4][rg] + bsv;
            }
        }
        return;
    }

    __syncthreads();   // reuse smem[0..4608] as output tile (stride 72)
    #pragma unroll
    for (int t4 = 0; t4 < 4; t4++) {
        int colL = (t4 << 4) + lm;
        float bsv = loadF(bias, col0 + colL, dtW);
        #pragma unroll
        for (int rg = 0; rg < 4; rg++) {
            int rowL = (w << 4) + (quad << 2) + rg;
            unsigned short hv = f2b(acc[t4][rg] + bsv);
            if (mode == 2) smem[colL * 72 + rowL] = hv;
            else           smem[rowL * 72 + colL] = hv;
        }
    }
    __syncthreads();
    const int g = t >> 2, cc = (t & 3) << 4;
    uint4 o0 = *(const uint4*)&smem[g * 72 + cc];
    uint4 o1 = *(const uint4*)&smem[g * 72 + cc + 8];
    unsigned short* o;
    if (mode == 0) {
        int b = row0 >> 9, n0b = row0 & 511, h = col0 >> 6;
        o = (unsigned short*)dst + ((size_t)(b * 12 + h) * 512 + n0b + g) * 64 + cc;
    } else if (mode == 2) {
        int b = row0 >> 9, n0b = row0 & 511, h = col0 >> 6;
        o = (unsigned short*)dst + ((size_t)(b * 12 + h) * 64 + g) * 512 + n0b + cc;
    } else {
        o = (unsigned short*)dst + (size_t)(row0 + g) * 768 + col0 + cc;
    }
    *(uint4*)o = o0;
    *(uint4*)(o + 8) = o1;
}

// ---------------------------------------------------------------------------
// MFMA attention (Round 10, unchanged). Block = 32 Q rows of one (b,h).
// ---------------------------------------------------------------------------
__global__ __launch_bounds__(256) void attn_kernel(
        const unsigned short* __restrict__ qh, const unsigned short* __restrict__ kh,
        const unsigned short* __restrict__ vT, const unsigned int* __restrict__ pm,
        const float* __restrict__ alphas, unsigned short* __restrict__ atted)
{
    __shared__ unsigned short P[32 * 512];      // 32 KB
    __shared__ float Zp[4][32][3];              // 1.5 KB
    __shared__ unsigned short Ost[32 * 72];     // 4.6 KB
    const int t = threadIdx.x;
    const int w = t >> 6, lane = t & 63, quad = lane >> 4, lm = lane & 15;
    const int id = blockIdx.x;
    const int bh = id % 96, qb2 = id / 96;
    const int b = bh / 12, h = bh % 12;
    const int n0 = qb2 << 5;

    // early mask loads: 6 u32/lane (2 row-sets x 3 orders); hide under QK^T
    const unsigned int* pmb = pm + (size_t)b * 8192 + (size_t)(qb2 << 1) * 256
                                 + (w << 6) + (lm << 2) + quad;
    unsigned int mw[2][3];
    #pragma unroll
    for (int s = 0; s < 2; s++) {
        mw[s][0] = pmb[s * 256];
        mw[s][1] = pmb[s * 256 + 65536];
        mw[s][2] = pmb[s * 256 + 131072];
    }

    float al[3];
    #pragma unroll
    for (int l = 0; l < 3; l++) al[l] = alphas[b * 3 + l];

    // Q fragments for both row-sets
    bf16x8 qa[2][2];
    #pragma unroll
    for (int s = 0; s < 2; s++) {
        const unsigned short* qrow = qh + ((size_t)(bh * 512 + n0 + (s << 4) + lm)) * 64
                                        + (quad << 3);
        qa[s][0] = *(const bf16x8*)qrow;
        qa[s][1] = *(const bf16x8*)(qrow + 32);
    }

    f32x4 acc[2][8];
    #pragma unroll
    for (int s = 0; s < 2; s++)
        #pragma unroll
        for (int i = 0; i < 8; i++) acc[s][i] = (f32x4){0.f, 0.f, 0.f, 0.f};

    const unsigned short* kb0 = kh + ((size_t)(bh * 512 + (w << 7) + lm)) * 64 + (quad << 3);
    __builtin_amdgcn_s_setprio(1);
    #pragma unroll
    for (int nt = 0; nt < 8; nt++) {
        const unsigned short* kr = kb0 + nt * (16 * 64);
        bf16x8 k0 = *(const bf16x8*)kr;
        bf16x8 k1 = *(const bf16x8*)(kr + 32);
        acc[0][nt] = __builtin_amdgcn_mfma_f32_16x16x32_bf16(qa[0][0], k0, acc[0][nt], 0, 0, 0);
        acc[1][nt] = __builtin_amdgcn_mfma_f32_16x16x32_bf16(qa[1][0], k0, acc[1][nt], 0, 0, 0);
        acc[0][nt] = __builtin_amdgcn_mfma_f32_16x16x32_bf16(qa[0][1], k1, acc[0][nt], 0, 0, 0);
        acc[1][nt] = __builtin_amdgcn_mfma_f32_16x16x32_bf16(qa[1][1], k1, acc[1][nt], 0, 0, 0);
    }
    __builtin_amdgcn_s_setprio(0);

    #pragma unroll
    for (int s = 0; s < 2; s++)
        #pragma unroll
        for (int nt = 0; nt < 8; nt++)
            #pragma unroll
            for (int rg = 0; rg < 4; rg++)
                acc[s][nt][rg] = __expf(acc[s][nt][rg] * 0.125f);

    unsigned int im[2][3];
    #pragma unroll
    for (int s = 0; s < 2; s++)
        #pragma unroll
        for (int l = 0; l < 3; l++) im[s][l] = ~mw[s][l];

    // Z pass: masked row-sums via sext-AND
    #pragma unroll
    for (int s = 0; s < 2; s++) {
        #pragma unroll
        for (int rg = 0; rg < 4; rg++) {
            float z0 = 0.f, z1 = 0.f, z2 = 0.f;
            #pragma unroll
            for (int nt = 0; nt < 8; nt++) {
                const int bp = (rg << 3) + nt;      // compile-time bit position
                const unsigned int e = __float_as_uint(acc[s][nt][rg]);
                z0 += __uint_as_float(e & (unsigned int)SBFE(im[s][0], bp));
                z1 += __uint_as_float(e & (unsigned int)SBFE(im[s][1], bp));
                z2 += __uint_as_float(e & (unsigned int)SBFE(im[s][2], bp));
            }
            #pragma unroll
            for (int off = 1; off < 16; off <<= 1) {
                z0 += __shfl_xor(z0, off);
                z1 += __shfl_xor(z1, off);
                z2 += __shfl_xor(z2, off);
            }
            if (lm == 0) {
                int row = (s << 4) + (quad << 2) + rg;
                Zp[w][row][0] = z0; Zp[w][row][1] = z1; Zp[w][row][2] = z2;
            }
        }
    }
    __syncthreads();

    // P pass: p = e * (sum_l keep_l * coef_l) + addu
    #pragma unroll
    for (int s = 0; s < 2; s++) {
        #pragma unroll
        for (int rg = 0; rg < 4; rg++) {
            const int row = (quad << 2) + rg;       // 0..15 within set
            const int prow = (s << 4) + row;
            float addu = 0.f;
            unsigned int cb[3];
            #pragma unroll
            for (int l = 0; l < 3; l++) {
                float Z = Zp[0][prow][l] + Zp[1][prow][l] + Zp[2][prow][l] + Zp[3][prow][l];
                float c;
                if (Z > 0.f) c = al[l] * __builtin_amdgcn_rcpf(Z);
                else { c = 0.f; addu += al[l] * (1.0f / 512.0f); }
                cb[l] = __float_as_uint(c);
            }
            const int key = row & 7;                // == prow & 7
            const int pbase = prow * 512 + (lm & 7) + (w << 7)
                            + ((((lm >> 3) ^ key) & 1) << 3);
            const int kk16 = (key >> 1) << 4;
            #pragma unroll
            for (int nt = 0; nt < 8; nt++) {
                const int bp = (rg << 3) + nt;
                float wsum = __uint_as_float(cb[0] & (unsigned int)SBFE(im[s][0], bp))
                           + __uint_as_float(cb[1] & (unsigned int)SBFE(im[s][1], bp))
                           + __uint_as_float(cb[2] & (unsigned int)SBFE(im[s][2], bp));
                float p = fmaf(acc[s][nt][rg], wsum, addu);
                unsigned int u = __float_as_uint(p) + 0x8000u;
                P[pbase + ((nt << 4) ^ kk16)] = (unsigned short)(u >> 16);
            }
        }
    }

    // 2-deep V prefetch issued before the barrier (V doesn't depend on P);
    // V fragments are shared by both row-sets.
    const unsigned short* vb = vT + ((size_t)(bh * 64 + (w << 4) + lm)) * 512 + (quad << 3);
    bf16x8 vp0 = *(const bf16x8*)vb;
    bf16x8 vp1 = *(const bf16x8*)(vb + 32);
    __syncthreads();

    f32x4 accO0 = (f32x4){0.f, 0.f, 0.f, 0.f};
    f32x4 accO1 = (f32x4){0.f, 0.f, 0.f, 0.f};
    __builtin_amdgcn_s_setprio(1);
    #pragma unroll
    for (int ks = 0; ks < 16; ks++) {
        const int po = ((((ks << 2) + quad) ^ (lm & 7)) << 3);
        bf16x8 pa0 = *(const bf16x8*)&P[lm * 512 + po];
        bf16x8 pa1 = *(const bf16x8*)&P[(lm + 16) * 512 + po];
        bf16x8 vf = (ks == 0) ? vp0 : (ks == 1) ? vp1 : *(const bf16x8*)(vb + (ks << 5));
        accO0 = __builtin_amdgcn_mfma_f32_16x16x32_bf16(pa0, vf, accO0, 0, 0, 0);
        accO1 = __builtin_amdgcn_mfma_f32_16x16x32_bf16(pa1, vf, accO1, 0, 0, 0);
    }
    __builtin_amdgcn_s_setprio(0);
    #pragma unroll
    for (int rg = 0; rg < 4; rg++) {
        unsigned int u0 = __float_as_uint(accO0[rg]) + 0x8000u;
        unsigned int u1 = __float_as_uint(accO1[rg]) + 0x8000u;
        Ost[((quad << 2) + rg) * 72 + (w << 4) + lm] = (unsigned short)(u0 >> 16);
        Ost[(16 + (quad << 2) + rg) * 72 + (w << 4) + lm] = (unsigned short)(u1 >> 16);
    }
    __syncthreads();
    const int r2 = t >> 4, c4 = t & 15;
    #pragma unroll
    for (int rr = 0; rr < 2; rr++) {
        const int row = (rr << 4) + r2;
        uint2 val = *(const uint2*)&Ost[row * 72 + (c4 << 2)];
        *(uint2*)&atted[((size_t)(b * 512 + n0 + row)) * 768 + (h << 6) + (c4 << 2)] = val;
    }
}

// ---------------------------------------------------------------------------
extern "C" void kernel_launch(void* const* d_in, const int* in_sizes, int n_in,
                              void* d_out, int out_size, void* d_ws, size_t ws_size,
                              hipStream_t stream)
{
    const void* v  = d_in[0];
    const void* k  = d_in[1];
    const void* q  = d_in[2];
    const void* mk = d_in[3];
    const void* Wv = d_in[6];
    const void* bv = d_in[7];
    const void* Wk = d_in[8];
    const void* bk = d_in[9];
    const void* Wq = d_in[10];
    const void* bq = d_in[11];
    const void* Wm = d_in[12];
    const void* bm = d_in[13];
    const void* pool_w = d_in[14];
    const void* pool_b = d_in[15];
    const void* w1 = d_in[16];
    const void* w2 = d_in[17];
    const void* b2 = d_in[18];

    char* ws = (char*)d_ws;
    int*   flags  = (int*)ws;                                   // 64 B
    float* alphas = (float*)(ws + 256);
    float* lg     = (float*)(ws + 1536);                        // 8x3 floats
    int*   cnt    = (int*)(ws + 1664);                          // 8 ints
    float* scores = (float*)(ws + 2048);                        // 16 KB
    float* ppart  = (float*)(ws + 33280);                       // 196 KB
    unsigned int* pm = (unsigned int*)(ws + 262144);            // 786 KB
    unsigned short* qh  = (unsigned short*)(ws + 1048576);      // 6.29 MB each
    unsigned short* kh  = (unsigned short*)(ws + 1048576 + 1 * 6291456L);
    unsigned short* vT  = (unsigned short*)(ws + 1048576 + 2 * 6291456L);
    unsigned short* vb  = (unsigned short*)(ws + 1048576 + 3 * 6291456L);
    unsigned short* kb  = (unsigned short*)(ws + 1048576 + 4 * 6291456L);
    unsigned short* qb  = (unsigned short*)(ws + 1048576 + 5 * 6291456L);
    unsigned short* atted = vb;  // alias: vb dead by attention time
    char* wt0 = ws + 1048576 + 6 * 6291456L;                    // 1.18 MB each
    unsigned short* WTv = (unsigned short*)(wt0);
    unsigned short* WTk = (unsigned short*)(wt0 + 1 * 1179648L);
    unsigned short* WTq = (unsigned short*)(wt0 + 2 * 1179648L);
    unsigned short* WTm = (unsigned short*)(wt0 + 3 * 1179648L);

    sniff_kernel<<<dim3(1), dim3(256), 0, stream>>>(
        (const unsigned int*)mk, (const unsigned int*)v, (const unsigned int*)Wv,
        flags, lg, cnt);
    prep_kernel<<<dim3(5632), dim3(256), 0, stream>>>(
        v, k, q, Wv, Wk, Wq, Wm, mk, pool_w, pool_b, flags,
        vb, kb, qb, WTv, WTk, WTq, WTm, pm, scores);
    gemm3_kernel<<<dim3(790, 3), dim3(256), 0, stream>>>(
        vb, kb, qb, v, k, q, WTv, WTk, WTq, bv, bk, bq, flags,
        (void*)vT, (void*)kh, (void*)qh, 2, 0, 0, scores, ppart);
    route_hid_kernel<<<dim3(12, 8), dim3(256), 0, stream>>>(
        w1, w2, b2, flags, ppart, lg, cnt, alphas);
    attn_kernel<<<dim3(1536), dim3(256), 0, stream>>>(qh, kh, vT, pm, alphas, atted);
    gemm3_kernel<<<dim3(768, 1), dim3(256), 0, stream>>>(
        atted, atted, atted, atted, atted, atted, WTm, WTm, WTm, bm, bm, bm, flags,
        d_out, d_out, d_out, 1, 1, 1, scores, ppart);
}

// Round 11
// 262.149 us; speedup vs baseline: 1.0073x; 1.0073x over previous
//
#include <hip/hip_runtime.h>
#include <hip/hip_bf16.h>
#include <stdint.h>

// ---------------------------------------------------------------------------
// SARoutingBlock. Round 18 = Round 16 exactly (best measured: 262.7 us).
// R17's global_load_lds staging A/B came back neutral (+1.4 us, in noise) ->
// reverted to the register-prefetch staging. Session summary: 300.4 -> 262.7
// via attn VALU diet + 2x-tile, prep/routing fusions (12 -> 6 launches),
// conv elision, rider blocks. attn pinned at ~58 us across 6 rewrites with
// bit-identical counters; gemm structure A/B'd both ways; launch graph
// minimal. This is the plateau configuration.
// ---------------------------------------------------------------------------

typedef __bf16 bf16x8 __attribute__((ext_vector_type(8)));
typedef float f32x4 __attribute__((ext_vector_type(4)));

#define NEGV -1e9f
// sign-extended single-bit extract: bit 'off' of x -> 0x0 / 0xFFFFFFFF
#define SBFE(x, off) (((int)((x) << (31 - (off)))) >> 31)

__device__ __forceinline__ float b2f(unsigned short h) {
    union { unsigned int u; float f; } x; x.u = ((unsigned int)h) << 16; return x.f;
}
__device__ __forceinline__ unsigned short f2b(float f) {
    union { float f; unsigned int u; } x; x.f = f;
    unsigned int u = x.u + 0x7FFFu + ((x.u >> 16) & 1u);
    return (unsigned short)(u >> 16);
}
__device__ __forceinline__ unsigned int packbf(unsigned int u0, unsigned int u1) {
    unsigned int r0 = (u0 + 0x7FFFu + ((u0 >> 16) & 1u)) >> 16;
    unsigned int r1 = (u1 + 0x7FFFu + ((u1 >> 16) & 1u)) & 0xFFFF0000u;
    return r0 | r1;
}
__device__ __forceinline__ uint4 load8bf(const void* base, size_t elemOff, int isF32) {
    if (!isF32) return *(const uint4*)((const unsigned short*)base + elemOff);
    const uint4* f = (const uint4*)((const float*)base + elemOff);
    uint4 a = f[0], b = f[1];
    uint4 r;
    r.x = packbf(a.x, a.y);
    r.y = packbf(a.z, a.w);
    r.z = packbf(b.x, b.y);
    r.w = packbf(b.z, b.w);
    return r;
}
__device__ __forceinline__ float loadF(const void* p, int idx, int isF32) {
    return isF32 ? ((const float*)p)[idx] : b2f(((const unsigned short*)p)[idx]);
}

// ---------------------------------------------------------------------------
// Sniffer: flags[0]=mask mode (0=i32,1=u8,2=f32,3=bf16); flags[1]=v/k/q dtype
// (0=bf16,1=f32); flags[2]=weights dtype. Also zeroes the hid/alpha
// accumulators (lg, cnt) for this iteration.
// ---------------------------------------------------------------------------
__global__ void sniff_kernel(const unsigned int* __restrict__ mp,
                             const unsigned int* __restrict__ vp,
                             const unsigned int* __restrict__ wp,
                             int* __restrict__ flags,
                             float* __restrict__ lg, int* __restrict__ cnt)
{
    __shared__ int oki, oku, okf, badv, badw;
    if (threadIdx.x < 24) lg[threadIdx.x] = 0.f;
    if (threadIdx.x >= 32 && threadIdx.x < 40) cnt[threadIdx.x - 32] = 0;
    if (threadIdx.x == 0) { oki = 1; oku = 1; okf = 1; badv = 0; badw = 0; }
    __syncthreads();
    int li = 1, lu = 1, lf = 1, bv = 0, bw = 0;
    const uint4* m4 = (const uint4*)mp;
    for (int i = threadIdx.x; i < 4096; i += 256) {
        uint4 u = m4[i];
        unsigned int ws[4] = {u.x, u.y, u.z, u.w};
        #pragma unroll
        for (int j = 0; j < 4; j++) {
            unsigned int w = ws[j];
            if (w > 1u) li = 0;
            if (w & 0xFEFEFEFEu) lu = 0;
            if (w != 0u && w != 0x3F800000u) lf = 0;
        }
    }
    const uint4* v4 = (const uint4*)vp;
    const uint4* w4 = (const uint4*)wp;
    for (int i = threadIdx.x; i < 2048; i += 256) {
        uint4 u = v4[i];
        uint4 u2 = w4[i];
        unsigned int wa[4] = {u.x, u.y, u.z, u.w};
        unsigned int wb[4] = {u2.x, u2.y, u2.z, u2.w};
        #pragma unroll
        for (int j = 0; j < 4; j++) {
            float f0 = b2f((unsigned short)(wa[j] & 0xFFFF));
            float f1 = b2f((unsigned short)(wa[j] >> 16));
            if (!(fabsf(f0) < 1e4f) || !(fabsf(f1) < 1e4f)) bv = 1;
            f0 = b2f((unsigned short)(wb[j] & 0xFFFF));
            f1 = b2f((unsigned short)(wb[j] >> 16));
            if (!(fabsf(f0) < 1e4f) || !(fabsf(f1) < 1e4f)) bw = 1;
        }
    }
    if (!li) atomicAnd(&oki, 0);
    if (!lu) atomicAnd(&oku, 0);
    if (!lf) atomicAnd(&okf, 0);
    if (bv) atomicOr(&badv, 1);
    if (bw) atomicOr(&badw, 1);
    __syncthreads();
    if (threadIdx.x == 0) {
        flags[0] = oki ? 0 : (oku ? 1 : (okf ? 2 : 3));
        flags[1] = badv;
        flags[2] = badw;
    }
}

// ---------------------------------------------------------------------------
// prep_kernel: fused conv_act (blocks 0..4607; early-exit when activations
// are already bf16) + conv_wt (4608..5183) + pack (5184..5567) +
// route_score (5568..5631). One launch; LDS union.
// ---------------------------------------------------------------------------
__global__ __launch_bounds__(256) void prep_kernel(
        const void* __restrict__ v, const void* __restrict__ k,
        const void* __restrict__ q,
        const void* __restrict__ W0, const void* __restrict__ W1,
        const void* __restrict__ W2, const void* __restrict__ W3,
        const void* __restrict__ masks,
        const void* __restrict__ pool_w, const void* __restrict__ pool_b,
        const int* __restrict__ flags,
        unsigned short* __restrict__ vb, unsigned short* __restrict__ kb,
        unsigned short* __restrict__ qb,
        unsigned short* __restrict__ T0, unsigned short* __restrict__ T1,
        unsigned short* __restrict__ T2, unsigned short* __restrict__ T3,
        unsigned int* __restrict__ pm, float* __restrict__ scores)
{
    __shared__ unsigned char shm[16384];
    const int t = threadIdx.x;
    const int id = blockIdx.x;

    if (id < 4608) {
        // ---- conv_act: only needed when activations are f32 ----
        const int dtV = flags[1];
        if (!dtV) return;             // bf16 input: gemm reads raw directly
        const int which = id / 1536, bx = id % 1536;
        const void* src = (which == 0) ? v : (which == 1) ? k : q;
        unsigned short* dst = (which == 0) ? vb : (which == 1) ? kb : qb;
        size_t off = ((size_t)bx * 256 + t) * 8;
        uint4 r = load8bf(src, off, 1);
        *(uint4*)(dst + off) = r;
        return;
    }

    if (id < 5184) {
        // ---- conv_wt: W[768][768] -> WT bf16 [n][k] (transposed) ----
        const int id2 = id - 4608;
        const int which = id2 / 144, bxw = id2 % 144;
        const int dtW = flags[2];
        const void* W = (which == 0) ? W0 : (which == 1) ? W1 : (which == 2) ? W2 : W3;
        unsigned short* T = (which == 0) ? T0 : (which == 1) ? T1 : (which == 2) ? T2 : T3;
        unsigned short (*tile)[65] = (unsigned short (*)[65])shm;   // 8320 B
        const int tk = (bxw / 12) << 6;
        const int tn = (bxw % 12) << 6;
        #pragma unroll
        for (int i = 0; i < 16; i++) {
            int idx = (i << 8) + t;
            int r = idx >> 6, c = idx & 63;
            tile[r][c] = f2b(loadF(W, (tk + r) * 768 + tn + c, dtW));
        }
        __syncthreads();
        #pragma unroll
        for (int i = 0; i < 16; i++) {
            int idx = (i << 8) + t;
            int rn = idx >> 6, ck = idx & 63;
            T[(size_t)(tn + rn) * 768 + tk + ck] = tile[ck][rn];
        }
        return;
    }

    if (id < 5568) {
        // ---- pack: mask bit-pack (R9 layout). One block packs 32 rows ----
        const int pb = id - 5184;
        unsigned char* flg = shm;                                    // 16384 B
        const int mode = flags[0];
        const size_t e0 = (size_t)pb * (32 * 512);
        if (mode == 0 || mode == 2) {
            const uint4* p = (const uint4*)((const unsigned int*)masks + e0);
            for (int i = t; i < 4096; i += 256) {
                uint4 u = p[i];
                int base = i << 2;
                flg[base + 0] = u.x ? 1 : 0;
                flg[base + 1] = u.y ? 1 : 0;
                flg[base + 2] = u.z ? 1 : 0;
                flg[base + 3] = u.w ? 1 : 0;
            }
        } else if (mode == 1) {
            const uint4* p = (const uint4*)((const unsigned char*)masks + e0);
            for (int i = t; i < 1024; i += 256) {
                uint4 u = p[i];
                unsigned int uu[4] = {u.x, u.y, u.z, u.w};
                int base = i << 4;
                #pragma unroll
                for (int k2 = 0; k2 < 4; k2++)
                    #pragma unroll
                    for (int bb = 0; bb < 4; bb++)
                        flg[base + k2 * 4 + bb] = ((uu[k2] >> (bb * 8)) & 0xFFu) ? 1 : 0;
            }
        } else {
            const uint4* p = (const uint4*)((const unsigned short*)masks + e0);
            for (int i = t; i < 2048; i += 256) {
                uint4 u = p[i];
                unsigned int uu[4] = {u.x, u.y, u.z, u.w};
                int base = i << 3;
                #pragma unroll
                for (int k2 = 0; k2 < 4; k2++) {
                    flg[base + k2 * 2 + 0] = (uu[k2] & 0xFFFFu) ? 1 : 0;
                    flg[base + k2 * 2 + 1] = (uu[k2] >> 16) ? 1 : 0;
                }
            }
        }
        __syncthreads();
        const int lbi = pb >> 4;            // l*8 + b
        const int qb0 = (pb & 15) << 1;     // first of 2 qb16 chunks
        for (int widx = t; widx < 512; widx += 256) {
            const int qq = widx >> 8, sub = widx & 255;
            const int w2 = sub >> 6, lm = (sub >> 2) & 15, quad = sub & 3;
            const unsigned char* fr = &flg[(((qq << 4) + (quad << 2)) << 9) + lm];
            unsigned int bits = 0;
            #pragma unroll
            for (int rg = 0; rg < 4; rg++)
                #pragma unroll
                for (int nt = 0; nt < 8; nt++)
                    bits |= ((unsigned int)(fr[(rg << 9) + (((w2 << 3) + nt) << 4)] & 1u))
                            << ((rg << 3) + nt);
            pm[(size_t)lbi * 8192 + (size_t)(qb0 + qq) * 256 + sub] = bits;
        }
        return;
    }

    // ---- route_score: raw pooling scores (64 rows/block, 4 thr/row) ----
    const int sid = id - 5568;
    const int b = sid >> 3, ch = sid & 7;
    const int dtV = flags[1], dtW = flags[2];
    float* pw = (float*)shm;                                        // 3072 B
    for (int d = t; d < 768; d += 256) pw[d] = loadF(pool_w, d, dtW);
    __syncthreads();
    const int r = t >> 2, c4 = t & 3;
    const int n = (ch << 6) + r;
    float dot = 0.f, asum = 0.f;
    if (!dtV) {
        const unsigned int* vr = (const unsigned int*)v + ((size_t)(b * 512 + n)) * 384;
        for (int j = 0; j < 96; j++) {
            int p = c4 + (j << 2);
            unsigned int u = vr[p];
            float f0 = b2f((unsigned short)(u & 0xFFFF));
            float f1 = b2f((unsigned short)(u >> 16));
            asum += fabsf(f0) + fabsf(f1);
            dot += f0 * pw[2 * p] + f1 * pw[2 * p + 1];
        }
    } else {
        const float* vf = (const float*)v + ((size_t)(b * 512 + n)) * 768;
        for (int j = 0; j < 48; j++) {
            float4 u = ((const float4*)vf)[c4 + (j << 2)];
            int e = (c4 + (j << 2)) << 2;
            asum += fabsf(u.x) + fabsf(u.y) + fabsf(u.z) + fabsf(u.w);
            dot += u.x * pw[e] + u.y * pw[e + 1] + u.z * pw[e + 2] + u.w * pw[e + 3];
        }
    }
    dot += __shfl_xor(dot, 1); dot += __shfl_xor(dot, 2);
    asum += __shfl_xor(asum, 1); asum += __shfl_xor(asum, 2);
    if (c4 == 0)
        scores[b * 512 + n] = (asum == 0.f) ? NEGV : dot + loadF(pool_b, 0, dtW);
}

// ---------------------------------------------------------------------------
// route_hid (+fused alpha): hidden units + partial logits; the last block of
// each batch (atomic counter) finalizes softmax -> alphas. Grid (12,8).
// ---------------------------------------------------------------------------
__global__ __launch_bounds__(256) void route_hid_kernel(
        const void* __restrict__ w1, const void* __restrict__ w2,
        const void* __restrict__ b2, const int* __restrict__ flags,
        const float* __restrict__ ppart,
        float* __restrict__ lg, int* __restrict__ cnt,
        float* __restrict__ alphas)
{
    __shared__ float pool[768];
    __shared__ float red[4][32];
    const int t = threadIdx.x;
    const int jc = blockIdx.x, b = blockIdx.y;
    const int dtW = flags[2];
    for (int d = t; d < 768; d += 256) {
        float a = 0.f;
        #pragma unroll
        for (int c = 0; c < 8; c++) a += ppart[((size_t)(b * 8 + c)) * 768 + d];
        pool[d] = a;
    }
    __syncthreads();
    const int jo = (t & 3) << 3;
    const int dr = t >> 2;
    float acc[8];
    #pragma unroll
    for (int j = 0; j < 8; j++) acc[j] = 0.f;
    for (int it = 0; it < 12; it++) {
        int d = (it << 6) + dr;
        float pv = pool[d];
        size_t off = (size_t)d * 384 + (jc << 5) + jo;
        if (!dtW) {
            uint4 u = *(const uint4*)((const unsigned short*)w1 + off);
            unsigned int uu[4] = {u.x, u.y, u.z, u.w};
            #pragma unroll
            for (int j2 = 0; j2 < 4; j2++) {
                acc[2 * j2]     += pv * b2f((unsigned short)(uu[j2] & 0xFFFF));
                acc[2 * j2 + 1] += pv * b2f((unsigned short)(uu[j2] >> 16));
            }
        } else {
            const float4* f = (const float4*)((const float*)w1 + off);
            float4 u0 = f[0], u1 = f[1];
            acc[0] += pv * u0.x; acc[1] += pv * u0.y;
            acc[2] += pv * u0.z; acc[3] += pv * u0.w;
            acc[4] += pv * u1.x; acc[5] += pv * u1.y;
            acc[6] += pv * u1.z; acc[7] += pv * u1.w;
        }
    }
    #pragma unroll
    for (int off = 4; off < 64; off <<= 1)
        #pragma unroll
        for (int j = 0; j < 8; j++) acc[j] += __shfl_xor(acc[j], off);
    const int w = t >> 6, lane = t & 63;
    if (lane < 4) {
        #pragma unroll
        for (int j = 0; j < 8; j++) red[w][lane * 8 + j] = acc[j];
    }
    __syncthreads();
    if (t < 32) {
        float h = red[0][t] + red[1][t] + red[2][t] + red[3][t];
        h = fmaxf(h, 0.f);
        int jg = (jc << 5) + t;
        float l0 = h * loadF(w2, jg * 3 + 0, dtW);
        float l1 = h * loadF(w2, jg * 3 + 1, dtW);
        float l2 = h * loadF(w2, jg * 3 + 2, dtW);
        #pragma unroll
        for (int off = 1; off < 32; off <<= 1) {
            l0 += __shfl_xor(l0, off);
            l1 += __shfl_xor(l1, off);
            l2 += __shfl_xor(l2, off);
        }
        if (t == 0) {
            atomicAdd(&lg[b * 3 + 0], l0);
            atomicAdd(&lg[b * 3 + 1], l1);
            atomicAdd(&lg[b * 3 + 2], l2);
            __threadfence();
            int old = atomicAdd(&cnt[b], 1);
            if (old == 11) {             // last block for this batch: finalize
                __threadfence();
                float g0 = atomicAdd(&lg[b * 3 + 0], 0.f) + loadF(b2, 0, dtW);
                float g1 = atomicAdd(&lg[b * 3 + 1], 0.f) + loadF(b2, 1, dtW);
                float g2 = atomicAdd(&lg[b * 3 + 2], 0.f) + loadF(b2, 2, dtW);
                float mm = fmaxf(g0, fmaxf(g1, g2));
                float e0 = __expf(g0 - mm), e1 = __expf(g1 - mm), e2 = __expf(g2 - mm);
                float ss = e0 + e1 + e2;
                alphas[b * 3 + 0] = e0 / ss;
                alphas[b * 3 + 1] = e1 / ss;
                alphas[b * 3 + 2] = e2 / ss;
            }
        }
    }
}

// ---------------------------------------------------------------------------
// Pipelined MFMA bf16 GEMM (64^2 tile, register prefetch) + route_sp riders.
// Up to 3 sub-gemms by blockIdx.y (x < 768). Blocks with x >= 768 run the
// fused softmax+pool (rid = (x-768)*3 + y, 64 active riders).
// X selected at runtime: raw input when activations are already bf16.
// mode 0: dst[b][h][n][64]; mode 1: dst[row][col] (bf16/f32); mode 2: V^T.
// ---------------------------------------------------------------------------
__global__ __launch_bounds__(256) void gemm3_kernel(
        const unsigned short* __restrict__ X0, const unsigned short* __restrict__ X1,
        const unsigned short* __restrict__ X2,
        const void* __restrict__ R0, const void* __restrict__ R1,
        const void* __restrict__ R2,
        const unsigned short* __restrict__ W0, const unsigned short* __restrict__ W1,
        const unsigned short* __restrict__ W2,
        const void* __restrict__ bias0, const void* __restrict__ bias1,
        const void* __restrict__ bias2,
        const int* __restrict__ flags,
        void* __restrict__ dst0, void* __restrict__ dst1, void* __restrict__ dst2,
        int m0, int m1, int m2,
        const float* __restrict__ scores, float* __restrict__ ppart)
{
    __shared__ unsigned short smem[8192];   // At[4096] + Bt[4096], 16 KB
    const int t = threadIdx.x;
    const int dtW = flags[2];
    const int dtOut = flags[1];

    if (blockIdx.x >= 768) {
        // ---- route_sp rider: fused softmax + pool (64 active blocks) ----
        const int rid = (blockIdx.x - 768) * 3 + blockIdx.y;
        if (rid >= 64) return;
        float* red = (float*)smem;          // 4 floats
        float* sl  = red + 4;               // 64 floats
        const int b = rid >> 3, ch = rid & 7;
        const int dtV = dtOut;

        float s0 = scores[b * 512 + t];
        float s1 = scores[b * 512 + 256 + t];
        float mx = fmaxf(s0, s1);
        #pragma unroll
        for (int off = 1; off < 64; off <<= 1) mx = fmaxf(mx, __shfl_xor(mx, off));
        if ((t & 63) == 0) red[t >> 6] = mx;
        __syncthreads();
        const float M = fmaxf(fmaxf(red[0], red[1]), fmaxf(red[2], red[3]));
        float e = __expf(s0 - M) + __expf(s1 - M);
        __syncthreads();
        float sm = e;
        #pragma unroll
        for (int off = 1; off < 64; off <<= 1) sm += __shfl_xor(sm, off);
        if ((t & 63) == 0) red[t >> 6] = sm;
        __syncthreads();
        const float SS = red[0] + red[1] + red[2] + red[3];

        if (t < 64) {
            float sc = scores[b * 512 + (ch << 6) + t];
            sl[t] = __expf(sc - M) / SS;
        }
        __syncthreads();

        const int d0 = t * 3;
        float a0 = 0.f, a1 = 0.f, a2 = 0.f;
        if (!dtV) {
            const unsigned short* vp = (const unsigned short*)R0
                + ((size_t)(b * 512 + (ch << 6))) * 768 + d0;
            #pragma unroll 4
            for (int r = 0; r < 64; r++) {
                float p = sl[r];
                a0 += b2f(vp[0]) * p; a1 += b2f(vp[1]) * p; a2 += b2f(vp[2]) * p;
                vp += 768;
            }
        } else {
            const float* vp = (const float*)R0 + ((size_t)(b * 512 + (ch << 6))) * 768 + d0;
            #pragma unroll 4
            for (int r = 0; r < 64; r++) {
                float p = sl[r];
                a0 += vp[0] * p; a1 += vp[1] * p; a2 += vp[2] * p;
                vp += 768;
            }
        }
        float* o = ppart + ((size_t)(b * 8 + ch)) * 768 + d0;
        o[0] = a0; o[1] = a1; o[2] = a2;
        return;
    }

    unsigned short* At = smem;
    unsigned short* Bt = smem + 4096;
    const int which = blockIdx.y;
    const unsigned short* Xc = (which == 0) ? X0 : (which == 1) ? X1 : X2;
    const void* Xr = (which == 0) ? R0 : (which == 1) ? R1 : R2;
    const unsigned short* X = dtOut ? Xc : (const unsigned short*)Xr;
    const unsigned short* WT = (which == 0) ? W0 : (which == 1) ? W1 : W2;
    const void* bias = (which == 0) ? bias0 : (which == 1) ? bias1 : bias2;
    void* dst = (which == 0) ? dst0 : (which == 1) ? dst1 : dst2;
    const int mode = (which == 0) ? m0 : (which == 1) ? m1 : m2;

    const int id = blockIdx.x;
    const int bx = id >> 6, by = id & 63;
    const int row0 = by << 6, col0 = bx << 6;
    const int w = t >> 6, lane = t & 63, quad = lane >> 4, lm = lane & 15;
    const int r0 = t >> 3, c0 = (t & 7) << 3;
    const int wr0 = r0 * 64 + (c0 ^ ((r0 & 7) << 3));   // +2048 for rows 32..63

    const unsigned short* xp  = X  + (size_t)(row0 + r0) * 768 + c0;
    const unsigned short* xp2 = xp + 32 * 768;
    const unsigned short* wp  = WT + (size_t)(col0 + r0) * 768 + c0;
    const unsigned short* wp2 = wp + 32 * 768;

    uint4 a0 = *(const uint4*)xp,  a1 = *(const uint4*)xp2;
    uint4 g0 = *(const uint4*)wp,  g1 = *(const uint4*)wp2;

    f32x4 acc[4];
    #pragma unroll
    for (int i = 0; i < 4; i++) acc[i] = (f32x4){0.f, 0.f, 0.f, 0.f};

    const int am = (w << 4) + lm;
    const int abase = am * 64, akey = (am & 7) << 3;

    for (int k0 = 0;;) {
        __syncthreads();
        *(uint4*)&At[wr0] = a0;        *(uint4*)&At[wr0 + 2048] = a1;
        *(uint4*)&Bt[wr0] = g0;        *(uint4*)&Bt[wr0 + 2048] = g1;
        __syncthreads();
        k0 += 64;
        if (k0 < 768) {    // prefetch next step; latency overlaps MFMAs below
            a0 = *(const uint4*)(xp + k0);  a1 = *(const uint4*)(xp2 + k0);
            g0 = *(const uint4*)(wp + k0);  g1 = *(const uint4*)(wp2 + k0);
        }
        #pragma unroll
        for (int ks = 0; ks < 2; ks++) {
            int ko = (quad << 3) + (ks << 5);
            bf16x8 afr = *(const bf16x8*)&At[abase + (ko ^ akey)];
            #pragma unroll
            for (int t4 = 0; t4 < 4; t4++) {
                int bn = (t4 << 4) + lm;
                bf16x8 bfr = *(const bf16x8*)&Bt[bn * 64 + (ko ^ ((bn & 7) << 3))];
                acc[t4] = __builtin_amdgcn_mfma_f32_16x16x32_bf16(afr, bfr, acc[t4], 0, 0, 0);
            }
        }
        if (k0 >= 768) break;
    }

    if (mode == 1 && dtOut) {
        #pragma unroll
        for (int t4 = 0; t4 < 4; t4++) {
            int col = col0 + (t4 << 4) + lm;
            float bsv = loadF(bias, col, dtW);
            #pragma unroll
            for (int rg = 0; rg < 4; rg++) {
                int row = row0 + (w << 4) + (quad << 2) + rg;
                ((float*)dst)[(size_t)row * 768 + col] = acc[t4][rg] + bsv;
            }
        }
        return;
    }

    __syncthreads();   // reuse smem[0..4608] as output tile (stride 72)
    #pragma unroll
    for (int t4 = 0; t4 < 4; t4++) {
        int colL = (t4 << 4) + lm;
        float bsv = loadF(bias, col0 + colL, dtW);
        #pragma unroll
        for (int rg = 0; rg < 4; rg++) {
            int rowL = (w << 4) + (quad << 2) + rg;
            unsigned short hv = f2b(acc[t4][rg] + bsv);
            if (mode == 2) smem[colL * 72 + rowL] = hv;
            else           smem[rowL * 72 + colL] = hv;
        }
    }
    __syncthreads();
    const int g = t >> 2, cc = (t & 3) << 4;
    uint4 o0 = *(const uint4*)&smem[g * 72 + cc];
    uint4 o1 = *(const uint4*)&smem[g * 72 + cc + 8];
    unsigned short* o;
    if (mode == 0) {
        int b = row0 >> 9, n0b = row0 & 511, h = col0 >> 6;
        o = (unsigned short*)dst + ((size_t)(b * 12 + h) * 512 + n0b + g) * 64 + cc;
    } else if (mode == 2) {
        int b = row0 >> 9, n0b = row0 & 511, h = col0 >> 6;
        o = (unsigned short*)dst + ((size_t)(b * 12 + h) * 64 + g) * 512 + n0b + cc;
    } else {
        o = (unsigned short*)dst + (size_t)(row0 + g) * 768 + col0 + cc;
    }
    *(uint4*)o = o0;
    *(uint4*)(o + 8) = o1;
}

// ---------------------------------------------------------------------------
// MFMA attention (Round 10, unchanged). Block = 32 Q rows of one (b,h).
// ---------------------------------------------------------------------------
__global__ __launch_bounds__(256) void attn_kernel(
        const unsigned short* __restrict__ qh, const unsigned short* __restrict__ kh,
        const unsigned short* __restrict__ vT, const unsigned int* __restrict__ pm,
        const float* __restrict__ alphas, unsigned short* __restrict__ atted)
{
    __shared__ unsigned short P[32 * 512];      // 32 KB
    __shared__ float Zp[4][32][3];              // 1.5 KB
    __shared__ unsigned short Ost[32 * 72];     // 4.6 KB
    const int t = threadIdx.x;
    const int w = t >> 6, lane = t & 63, quad = lane >> 4, lm = lane & 15;
    const int id = blockIdx.x;
    const int bh = id % 96, qb2 = id / 96;
    const int b = bh / 12, h = bh % 12;
    const int n0 = qb2 << 5;

    // early mask loads: 6 u32/lane (2 row-sets x 3 orders); hide under QK^T
    const unsigned int* pmb = pm + (size_t)b * 8192 + (size_t)(qb2 << 1) * 256
                                 + (w << 6) + (lm << 2) + quad;
    unsigned int mw[2][3];
    #pragma unroll
    for (int s = 0; s < 2; s++) {
        mw[s][0] = pmb[s * 256];
        mw[s][1] = pmb[s * 256 + 65536];
        mw[s][2] = pmb[s * 256 + 131072];
    }

    float al[3];
    #pragma unroll
    for (int l = 0; l < 3; l++) al[l] = alphas[b * 3 + l];

    // Q fragments for both row-sets
    bf16x8 qa[2][2];
    #pragma unroll
    for (int s = 0; s < 2; s++) {
        const unsigned short* qrow = qh + ((size_t)(bh * 512 + n0 + (s << 4) + lm)) * 64
                                        + (quad << 3);
        qa[s][0] = *(const bf16x8*)qrow;
        qa[s][1] = *(const bf16x8*)(qrow + 32);
    }

    f32x4 acc[2][8];
    #pragma unroll
    for (int s = 0; s < 2; s++)
        #pragma unroll
        for (int i = 0; i < 8; i++) acc[s][i] = (f32x4){0.f, 0.f, 0.f, 0.f};

    const unsigned short* kb0 = kh + ((size_t)(bh * 512 + (w << 7) + lm)) * 64 + (quad << 3);
    __builtin_amdgcn_s_setprio(1);
    #pragma unroll
    for (int nt = 0; nt < 8; nt++) {
        const unsigned short* kr = kb0 + nt * (16 * 64);
        bf16x8 k0 = *(const bf16x8*)kr;
        bf16x8 k1 = *(const bf16x8*)(kr + 32);
        acc[0][nt] = __builtin_amdgcn_mfma_f32_16x16x32_bf16(qa[0][0], k0, acc[0][nt], 0, 0, 0);
        acc[1][nt] = __builtin_amdgcn_mfma_f32_16x16x32_bf16(qa[1][0], k0, acc[1][nt], 0, 0, 0);
        acc[0][nt] = __builtin_amdgcn_mfma_f32_16x16x32_bf16(qa[0][1], k1, acc[0][nt], 0, 0, 0);
        acc[1][nt] = __builtin_amdgcn_mfma_f32_16x16x32_bf16(qa[1][1], k1, acc[1][nt], 0, 0, 0);
    }
    __builtin_amdgcn_s_setprio(0);

    #pragma unroll
    for (int s = 0; s < 2; s++)
        #pragma unroll
        for (int nt = 0; nt < 8; nt++)
            #pragma unroll
            for (int rg = 0; rg < 4; rg++)
                acc[s][nt][rg] = __expf(acc[s][nt][rg] * 0.125f);

    unsigned int im[2][3];
    #pragma unroll
    for (int s = 0; s < 2; s++)
        #pragma unroll
        for (int l = 0; l < 3; l++) im[s][l] = ~mw[s][l];

    // Z pass: masked row-sums via sext-AND
    #pragma unroll
    for (int s = 0; s < 2; s++) {
        #pragma unroll
        for (int rg = 0; rg < 4; rg++) {
            float z0 = 0.f, z1 = 0.f, z2 = 0.f;
            #pragma unroll
            for (int nt = 0; nt < 8; nt++) {
                const int bp = (rg << 3) + nt;      // compile-time bit position
                const unsigned int e = __float_as_uint(acc[s][nt][rg]);
                z0 += __uint_as_float(e & (unsigned int)SBFE(im[s][0], bp));
                z1 += __uint_as_float(e & (unsigned int)SBFE(im[s][1], bp));
                z2 += __uint_as_float(e & (unsigned int)SBFE(im[s][2], bp));
            }
            #pragma unroll
            for (int off = 1; off < 16; off <<= 1) {
                z0 += __shfl_xor(z0, off);
                z1 += __shfl_xor(z1, off);
                z2 += __shfl_xor(z2, off);
            }
            if (lm == 0) {
                int row = (s << 4) + (quad << 2) + rg;
                Zp[w][row][0] = z0; Zp[w][row][1] = z1; Zp[w][row][2] = z2;
            }
        }
    }
    __syncthreads();

    // P pass: p = e * (sum_l keep_l * coef_l) + addu
    #pragma unroll
    for (int s = 0; s < 2; s++) {
        #pragma unroll
        for (int rg = 0; rg < 4; rg++) {
            const int row = (quad << 2) + rg;       // 0..15 within set
            const int prow = (s << 4) + row;
            float addu = 0.f;
            unsigned int cb[3];
            #pragma unroll
            for (int l = 0; l < 3; l++) {
                float Z = Zp[0][prow][l] + Zp[1][prow][l] + Zp[2][prow][l] + Zp[3][prow][l];
                float c;
                if (Z > 0.f) c = al[l] * __builtin_amdgcn_rcpf(Z);
                else { c = 0.f; addu += al[l] * (1.0f / 512.0f); }
                cb[l] = __float_as_uint(c);
            }
            const int key = row & 7;                // == prow & 7
            const int pbase = prow * 512 + (lm & 7) + (w << 7)
                            + ((((lm >> 3) ^ key) & 1) << 3);
            const int kk16 = (key >> 1) << 4;
            #pragma unroll
            for (int nt = 0; nt < 8; nt++) {
                const int bp = (rg << 3) + nt;
                float wsum = __uint_as_float(cb[0] & (unsigned int)SBFE(im[s][0], bp))
                           + __uint_as_float(cb[1] & (unsigned int)SBFE(im[s][1], bp))
                           + __uint_as_float(cb[2] & (unsigned int)SBFE(im[s][2], bp));
                float p = fmaf(acc[s][nt][rg], wsum, addu);
                unsigned int u = __float_as_uint(p) + 0x8000u;
                P[pbase + ((nt << 4) ^ kk16)] = (unsigned short)(u >> 16);
            }
        }
    }

    // 2-deep V prefetch issued before the barrier (V doesn't depend on P);
    // V fragments are shared by both row-sets.
    const unsigned short* vb = vT + ((size_t)(bh * 64 + (w << 4) + lm)) * 512 + (quad << 3);
    bf16x8 vp0 = *(const bf16x8*)vb;
    bf16x8 vp1 = *(const bf16x8*)(vb + 32);
    __syncthreads();

    f32x4 accO0 = (f32x4){0.f, 0.f, 0.f, 0.f};
    f32x4 accO1 = (f32x4){0.f, 0.f, 0.f, 0.f};
    __builtin_amdgcn_s_setprio(1);
    #pragma unroll
    for (int ks = 0; ks < 16; ks++) {
        const int po = ((((ks << 2) + quad) ^ (lm & 7)) << 3);
        bf16x8 pa0 = *(const bf16x8*)&P[lm * 512 + po];
        bf16x8 pa1 = *(const bf16x8*)&P[(lm + 16) * 512 + po];
        bf16x8 vf = (ks == 0) ? vp0 : (ks == 1) ? vp1 : *(const bf16x8*)(vb + (ks << 5));
        accO0 = __builtin_amdgcn_mfma_f32_16x16x32_bf16(pa0, vf, accO0, 0, 0, 0);
        accO1 = __builtin_amdgcn_mfma_f32_16x16x32_bf16(pa1, vf, accO1, 0, 0, 0);
    }
    __builtin_amdgcn_s_setprio(0);
    #pragma unroll
    for (int rg = 0; rg < 4; rg++) {
        unsigned int u0 = __float_as_uint(accO0[rg]) + 0x8000u;
        unsigned int u1 = __float_as_uint(accO1[rg]) + 0x8000u;
        Ost[((quad << 2) + rg) * 72 + (w << 4) + lm] = (unsigned short)(u0 >> 16);
        Ost[(16 + (quad << 2) + rg) * 72 + (w << 4) + lm] = (unsigned short)(u1 >> 16);
    }
    __syncthreads();
    const int r2 = t >> 4, c4 = t & 15;
    #pragma unroll
    for (int rr = 0; rr < 2; rr++) {
        const int row = (rr << 4) + r2;
        uint2 val = *(const uint2*)&Ost[row * 72 + (c4 << 2)];
        *(uint2*)&atted[((size_t)(b * 512 + n0 + row)) * 768 + (h << 6) + (c4 << 2)] = val;
    }
}

// ---------------------------------------------------------------------------
extern "C" void kernel_launch(void* const* d_in, const int* in_sizes, int n_in,
                              void* d_out, int out_size, void* d_ws, size_t ws_size,
                              hipStream_t stream)
{
    const void* v  = d_in[0];
    const void* k  = d_in[1];
    const void* q  = d_in[2];
    const void* mk = d_in[3];
    const void* Wv = d_in[6];
    const void* bv = d_in[7];
    const void* Wk = d_in[8];
    const void* bk = d_in[9];
    const void* Wq = d_in[10];
    const void* bq = d_in[11];
    const void* Wm = d_in[12];
    const void* bm = d_in[13];
    const void* pool_w = d_in[14];
    const void* pool_b = d_in[15];
    const void* w1 = d_in[16];
    const void* w2 = d_in[17];
    const void* b2 = d_in[18];

    char* ws = (char*)d_ws;
    int*   flags  = (int*)ws;                                   // 64 B
    float* alphas = (float*)(ws + 256);
    float* lg     = (float*)(ws + 1536);                        // 8x3 floats
    int*   cnt    = (int*)(ws + 1664);                          // 8 ints
    float* scores = (float*)(ws + 2048);                        // 16 KB
    float* ppart  = (float*)(ws + 33280);                       // 196 KB
    unsigned int* pm = (unsigned int*)(ws + 262144);            // 786 KB
    unsigned short* qh  = (unsigned short*)(ws + 1048576);      // 6.29 MB each
    unsigned short* kh  = (unsigned short*)(ws + 1048576 + 1 * 6291456L);
    unsigned short* vT  = (unsigned short*)(ws + 1048576 + 2 * 6291456L);
    unsigned short* vb  = (unsigned short*)(ws + 1048576 + 3 * 6291456L);
    unsigned short* kb  = (unsigned short*)(ws + 1048576 + 4 * 6291456L);
    unsigned short* qb  = (unsigned short*)(ws + 1048576 + 5 * 6291456L);
    unsigned short* atted = vb;  // alias: vb dead by attention time
    char* wt0 = ws + 1048576 + 6 * 6291456L;                    // 1.18 MB each
    unsigned short* WTv = (unsigned short*)(wt0);
    unsigned short* WTk = (unsigned short*)(wt0 + 1 * 1179648L);
    unsigned short* WTq = (unsigned short*)(wt0 + 2 * 1179648L);
    unsigned short* WTm = (unsigned short*)(wt0 + 3 * 1179648L);

    sniff_kernel<<<dim3(1), dim3(256), 0, stream>>>(
        (const unsigned int*)mk, (const unsigned int*)v, (const unsigned int*)Wv,
        flags, lg, cnt);
    prep_kernel<<<dim3(5632), dim3(256), 0, stream>>>(
        v, k, q, Wv, Wk, Wq, Wm, mk, pool_w, pool_b, flags,
        vb, kb, qb, WTv, WTk, WTq, WTm, pm, scores);
    gemm3_kernel<<<dim3(790, 3), dim3(256), 0, stream>>>(
        vb, kb, qb, v, k, q, WTv, WTk, WTq, bv, bk, bq, flags,
        (void*)vT, (void*)kh, (void*)qh, 2, 0, 0, scores, ppart);
    route_hid_kernel<<<dim3(12, 8), dim3(256), 0, stream>>>(
        w1, w2, b2, flags, ppart, lg, cnt, alphas);
    attn_kernel<<<dim3(1536), dim3(256), 0, stream>>>(qh, kh, vT, pm, alphas, atted);
    gemm3_kernel<<<dim3(768, 1), dim3(256), 0, stream>>>(
        atted, atted, atted, atted, atted, atted, WTm, WTm, WTm, bm, bm, bm, flags,
        d_out, d_out, d_out, 1, 1, 1, scores, ppart);
}